// Round 1
// baseline (147.704 us; speedup 1.0000x reference)
//
#include <hip/hip_runtime.h>
#include <math.h>

#define BB 512
#define SS 128
#define VV 2048

constexpr float LSc    = 0.1f;   // label smoothing
constexpr float END_W  = 3.0f;
constexpr float CHAR_W = 0.2f;
constexpr float LEN_P  = 0.3f;

// ---------------- Kernel 1: per-row softmax stats (one block per (b,s) row) ----
__global__ __launch_bounds__(256) void k_rows(const float* __restrict__ x,
                                              const int* __restrict__ tgt,
                                              float* __restrict__ ce,
                                              int* __restrict__ preds) {
    const int row  = blockIdx.x;
    const int tid  = threadIdx.x;
    const int lane = tid & 63;
    const int wv   = tid >> 6;
    const float* rp = x + (size_t)row * VV;
    const int t = tgt[row];

    // 8 floats per thread: indices [tid*4 .. tid*4+3] and [1024+tid*4 .. +3]
    float4 a = *(const float4*)(rp + tid * 4);
    float4 c = *(const float4*)(rp + 1024 + tid * 4);
    float v[8] = {a.x, a.y, a.z, a.w, c.x, c.y, c.z, c.w};

    __shared__ float s_m[4]; __shared__ int s_i[4];
    __shared__ float s_s[4], s_e[4];
    __shared__ float s_M;   __shared__ int s_A;
    __shared__ float s_xt;

    // owner of x[target] publishes it
    {
        int base0 = tid * 4, base1 = 1024 + tid * 4;
        if (t >= base0 && t < base0 + 4) s_xt = v[t - base0];
        if (t >= base1 && t < base1 + 4) s_xt = v[4 + (t - base1)];
    }

    // per-thread max + argmax (first-occurrence tie-break)
    float m = v[0]; int mi = tid * 4;
#pragma unroll
    for (int k = 1; k < 8; ++k) {
        int idx = (k < 4) ? (tid * 4 + k) : (1024 + tid * 4 + (k - 4));
        if (v[k] > m || (v[k] == m && idx < mi)) { m = v[k]; mi = idx; }
    }
#pragma unroll
    for (int off = 32; off >= 1; off >>= 1) {
        float om = __shfl_xor(m, off);
        int   oi = __shfl_xor(mi, off);
        if (om > m || (om == m && oi < mi)) { m = om; mi = oi; }
    }
    if (lane == 0) { s_m[wv] = m; s_i[wv] = mi; }
    __syncthreads();
    if (tid == 0) {
        float M = s_m[0]; int A = s_i[0];
        for (int w = 1; w < 4; ++w)
            if (s_m[w] > M || (s_m[w] == M && s_i[w] < A)) { M = s_m[w]; A = s_i[w]; }
        s_M = M; s_A = A;
    }
    __syncthreads();
    const float M = s_M;

    float ssum = 0.f, esum = 0.f;
#pragma unroll
    for (int k = 0; k < 8; ++k) { ssum += v[k]; esum += __expf(v[k] - M); }
#pragma unroll
    for (int off = 32; off >= 1; off >>= 1) {
        ssum += __shfl_xor(ssum, off);
        esum += __shfl_xor(esum, off);
    }
    if (lane == 0) { s_s[wv] = ssum; s_e[wv] = esum; }
    __syncthreads();
    if (tid == 0) {
        float S2 = 0.f, E = 0.f;
        for (int w = 0; w < 4; ++w) { S2 += s_s[w]; E += s_e[w]; }
        float lse    = M + logf(E);
        float nll    = lse - s_xt;              // -log p[target]
        float mean_x = S2 * (1.0f / VV);
        float cev    = (1.0f - LSc) * nll + LSc * (lse - mean_x);
        ce[row]    = (t != 0) ? cev : 0.0f;
        preds[row] = s_A;
    }
}

// ---------------- init: zero the 5 accumulators + flag -------------------------
__global__ void k_init(float* acc, int* flag) {
    for (int i = 0; i < 5; ++i) acc[i] = 0.f;
    *flag = 0;
}

// ---------------- Kernel 2: per-batch stats (one block per batch) --------------
__global__ __launch_bounds__(128) void k_batch(const int* __restrict__ tgt,
                                               const int* __restrict__ preds,
                                               const float* __restrict__ ce,
                                               float* __restrict__ acc,
                                               int* __restrict__ flag) {
    const int b = blockIdx.x;
    const int j = threadIdx.x;

    __shared__ int   st[SS];
    __shared__ int   sp[SS];
    __shared__ int   ired[128];
    __shared__ float fred[128][4];

    int   t = tgt[b * SS + j];
    int   p = preds[b * SS + j];
    float c = ce[b * SS + j];
    st[j] = t; sp[j] = p;

    // pack three counts: lens | plen<<8 | valid(first S-2)<<16
    ired[j] = (t != 0 ? 1 : 0) | ((p != 0 ? 1 : 0) << 8)
            | (((t != 0 && j < SS - 2) ? 1 : 0) << 16);
    __syncthreads();
    for (int off = 64; off >= 1; off >>= 1) {
        if (j < off) ired[j] += ired[j + off];
        __syncthreads();
    }
    const int r  = ired[0];
    const int L  = r & 255;
    const int P  = (r >> 8) & 255;
    const int VC = r >> 16;

    // position weight (exact replication of the reference where-chain)
    float w = 1.0f;
    if (L > 0 && j < L) {
        w = 1.0f + 0.5f * ((float)j / (float)L);
        if (j == L - 1)                w = END_W * 1.5f;   // 4.5
        else if (L >= 2 && j == L - 2) w = END_W * 1.0f;   // 3.0
        else if (L >= 3 && j == L - 3) w = END_W * 0.8f;   // 2.4
        if (L >= 4 && j >= L / 3 && j < (2 * L) / 3) w *= 1.3f;
        if (L <= 4) w *= 1.2f;
    }

    float big = 0.f, tri = 0.f;
    if (j < SS - 1) {
        bool pb = sp[j] == sp[j + 1];
        bool tb = st[j] == st[j + 1];
        bool mb = pb && tb && (sp[j] == st[j]);
        float wt = (j >= SS - 3) ? 2.25f : 1.0f;           // 1.5^2
        big = ((pb ? 1.f : 0.f) + (tb ? 1.f : 0.f) - 2.f * (mb ? 1.f : 0.f)) * wt;
    }
    if (j < SS - 2) {
        bool pt = (sp[j] == sp[j + 1]) && (sp[j + 1] == sp[j + 2]);
        bool tt = (st[j] == st[j + 1]) && (st[j + 1] == st[j + 2]);
        bool mt = pt && tt && (sp[j] == st[j]);
        float wt = (j >= SS - 4) ? 4.0f : 1.0f;            // 2.0^2
        tri = ((pt ? 1.f : 0.f) + (tt ? 1.f : 0.f) - 2.f * (mt ? 1.f : 0.f)) * wt;
    }

    fred[j][0] = c * w;
    fred[j][1] = w;
    fred[j][2] = big;
    fred[j][3] = tri;
    __syncthreads();
    for (int off = 64; off >= 1; off >>= 1) {
        if (j < off) {
            fred[j][0] += fred[j + off][0];
            fred[j][1] += fred[j + off][1];
            fred[j][2] += fred[j + off][2];
            fred[j][3] += fred[j + off][3];
        }
        __syncthreads();
    }
    if (j == 0) {
        atomicAdd(&acc[0], fred[0][0]);   // sum(ce*bw)
        atomicAdd(&acc[1], fred[0][1]);   // sum(bw)
        float diff   = fabsf((float)P - (float)L);
        float factor = 1.0f + (P < L ? 0.5f : 0.f) + (P <= 3 ? 0.3f : 0.f);
        atomicAdd(&acc[2], diff * factor);
        atomicAdd(&acc[3], fred[0][2]);   // bigram
        atomicAdd(&acc[4], fred[0][3]);   // trigram
        if (VC > 0) atomicOr(flag, 1);
    }
}

// ---------------- Kernel 3: final combine --------------------------------------
__global__ void k_final(const float* __restrict__ acc,
                        const int* __restrict__ flag,
                        float* __restrict__ out) {
    float wl = acc[0] / acc[1];
    float lp = LEN_P * acc[2] * (1.0f / BB);
    float bg = acc[3] / (float)(BB * (SS - 1) * VV);
    float tg = acc[4] / (float)(BB * (SS - 2) * VV);
    float ng = bg + ((*flag) ? 1.5f * tg : 0.f);
    out[0] = wl * 0.7f + lp * 0.2f + CHAR_W * ng * 0.1f;
}

extern "C" void kernel_launch(void* const* d_in, const int* in_sizes, int n_in,
                              void* d_out, int out_size, void* d_ws, size_t ws_size,
                              hipStream_t stream) {
    const float* x   = (const float*)d_in[0];   // [512,128,2048] f32
    const int*   tgt = (const int*)d_in[1];     // [512,128] i32
    float*       out = (float*)d_out;           // scalar f32

    float* ce    = (float*)d_ws;                              // 65536 f32
    int*   preds = (int*)((char*)d_ws + (size_t)BB * SS * 4); // 65536 i32
    float* acc   = (float*)((char*)d_ws + (size_t)2 * BB * SS * 4);
    int*   flag  = (int*)(acc + 5);

    k_rows<<<BB * SS, 256, 0, stream>>>(x, tgt, ce, preds);
    k_init<<<1, 1, 0, stream>>>(acc, flag);
    k_batch<<<BB, 128, 0, stream>>>(tgt, preds, ce, acc, flag);
    k_final<<<1, 1, 0, stream>>>(acc, flag, out);
}

// Round 2
// 137.607 us; speedup vs baseline: 1.0734x; 1.0734x over previous
//
#include <hip/hip_runtime.h>
#include <math.h>

#define BB 512
#define SS 128
#define VV 2048

constexpr float LSc    = 0.1f;   // label smoothing
constexpr float END_W  = 3.0f;
constexpr float CHAR_W = 0.2f;
constexpr float LEN_P  = 0.3f;

// ---------------- Kernel 1: one WAVE per (b,s) row — no LDS, no barriers -------
// 64 lanes x 32 floats = full 2048-wide row in registers; all reductions via
// __shfl_xor. Block = 4 independent waves = 4 rows.
__global__ __launch_bounds__(256) void k_rows(const float* __restrict__ x,
                                              const int* __restrict__ tgt,
                                              float* __restrict__ ce,
                                              int* __restrict__ preds,
                                              float* __restrict__ acc,
                                              int* __restrict__ flag) {
    // fold k_init: zero the scalar accumulators (visible to k_batch via stream order)
    if (blockIdx.x == 0 && threadIdx.x == 0) {
        for (int i = 0; i < 5; ++i) acc[i] = 0.f;
        *flag = 0;
    }

    const int lane = threadIdx.x & 63;
    const int row  = blockIdx.x * 4 + (threadIdx.x >> 6);
    const float* rp = x + (size_t)row * VV;
    const int t = tgt[row];

    // lane holds elements {k*256 + lane*4 + e : k<8, e<4} — coalesced dwordx4
    float4 v[8];
#pragma unroll
    for (int k = 0; k < 8; ++k)
        v[k] = *(const float4*)(rp + k * 256 + lane * 4);

    // ---- max + argmax (first-occurrence tie-break) ----
    float m = v[0].x; int mi = lane * 4;
#pragma unroll
    for (int k = 0; k < 8; ++k) {
        const float f0 = v[k].x, f1 = v[k].y, f2 = v[k].z, f3 = v[k].w;
        const int base = k * 256 + lane * 4;
        if (f0 > m) { m = f0; mi = base;     }
        if (f1 > m) { m = f1; mi = base + 1; }
        if (f2 > m) { m = f2; mi = base + 2; }
        if (f3 > m) { m = f3; mi = base + 3; }
    }
#pragma unroll
    for (int off = 1; off < 64; off <<= 1) {
        float om = __shfl_xor(m, off);
        int   oi = __shfl_xor(mi, off);
        if (om > m || (om == m && oi < mi)) { m = om; mi = oi; }
    }
    // all lanes now hold row max m and argmax mi

    // ---- fused sum / expsum / x[target] ----
    float ssum = 0.f, esum = 0.f, xt = 0.f;
#pragma unroll
    for (int k = 0; k < 8; ++k) {
        const float f0 = v[k].x, f1 = v[k].y, f2 = v[k].z, f3 = v[k].w;
        const int base = k * 256 + lane * 4;
        ssum += f0 + f1 + f2 + f3;
        esum += __expf(f0 - m) + __expf(f1 - m) + __expf(f2 - m) + __expf(f3 - m);
        if (base     == t) xt = f0;
        if (base + 1 == t) xt = f1;
        if (base + 2 == t) xt = f2;
        if (base + 3 == t) xt = f3;
    }
#pragma unroll
    for (int off = 1; off < 64; off <<= 1) {
        ssum += __shfl_xor(ssum, off);
        esum += __shfl_xor(esum, off);
        xt   += __shfl_xor(xt,   off);
    }

    if (lane == 0) {
        float lse = m + logf(esum);
        float nll = lse - xt;                          // -log p[target]
        float cev = (1.0f - LSc) * nll + LSc * (lse - ssum * (1.0f / VV));
        ce[row]    = (t != 0) ? cev : 0.0f;
        preds[row] = mi;
    }
}

// ---------------- Kernel 2: per-batch stats (one block per batch) --------------
__global__ __launch_bounds__(128) void k_batch(const int* __restrict__ tgt,
                                               const int* __restrict__ preds,
                                               const float* __restrict__ ce,
                                               float* __restrict__ acc,
                                               int* __restrict__ flag) {
    const int b = blockIdx.x;
    const int j = threadIdx.x;

    __shared__ int   st[SS];
    __shared__ int   sp[SS];
    __shared__ int   ired[128];
    __shared__ float fred[128][4];

    int   t = tgt[b * SS + j];
    int   p = preds[b * SS + j];
    float c = ce[b * SS + j];
    st[j] = t; sp[j] = p;

    // pack three counts: lens | plen<<8 | valid(first S-2)<<16
    ired[j] = (t != 0 ? 1 : 0) | ((p != 0 ? 1 : 0) << 8)
            | (((t != 0 && j < SS - 2) ? 1 : 0) << 16);
    __syncthreads();
    for (int off = 64; off >= 1; off >>= 1) {
        if (j < off) ired[j] += ired[j + off];
        __syncthreads();
    }
    const int r  = ired[0];
    const int L  = r & 255;
    const int P  = (r >> 8) & 255;
    const int VC = r >> 16;

    // position weight (exact replication of the reference where-chain)
    float w = 1.0f;
    if (L > 0 && j < L) {
        w = 1.0f + 0.5f * ((float)j / (float)L);
        if (j == L - 1)                w = END_W * 1.5f;   // 4.5
        else if (L >= 2 && j == L - 2) w = END_W * 1.0f;   // 3.0
        else if (L >= 3 && j == L - 3) w = END_W * 0.8f;   // 2.4
        if (L >= 4 && j >= L / 3 && j < (2 * L) / 3) w *= 1.3f;
        if (L <= 4) w *= 1.2f;
    }

    float big = 0.f, tri = 0.f;
    if (j < SS - 1) {
        bool pb = sp[j] == sp[j + 1];
        bool tb = st[j] == st[j + 1];
        bool mb = pb && tb && (sp[j] == st[j]);
        float wt = (j >= SS - 3) ? 2.25f : 1.0f;           // 1.5^2
        big = ((pb ? 1.f : 0.f) + (tb ? 1.f : 0.f) - 2.f * (mb ? 1.f : 0.f)) * wt;
    }
    if (j < SS - 2) {
        bool pt = (sp[j] == sp[j + 1]) && (sp[j + 1] == sp[j + 2]);
        bool tt = (st[j] == st[j + 1]) && (st[j + 1] == st[j + 2]);
        bool mt = pt && tt && (sp[j] == st[j]);
        float wt = (j >= SS - 4) ? 4.0f : 1.0f;            // 2.0^2
        tri = ((pt ? 1.f : 0.f) + (tt ? 1.f : 0.f) - 2.f * (mt ? 1.f : 0.f)) * wt;
    }

    fred[j][0] = c * w;
    fred[j][1] = w;
    fred[j][2] = big;
    fred[j][3] = tri;
    __syncthreads();
    for (int off = 64; off >= 1; off >>= 1) {
        if (j < off) {
            fred[j][0] += fred[j + off][0];
            fred[j][1] += fred[j + off][1];
            fred[j][2] += fred[j + off][2];
            fred[j][3] += fred[j + off][3];
        }
        __syncthreads();
    }
    if (j == 0) {
        atomicAdd(&acc[0], fred[0][0]);   // sum(ce*bw)
        atomicAdd(&acc[1], fred[0][1]);   // sum(bw)
        float diff   = fabsf((float)P - (float)L);
        float factor = 1.0f + (P < L ? 0.5f : 0.f) + (P <= 3 ? 0.3f : 0.f);
        atomicAdd(&acc[2], diff * factor);
        atomicAdd(&acc[3], fred[0][2]);   // bigram
        atomicAdd(&acc[4], fred[0][3]);   // trigram
        if (VC > 0) atomicOr(flag, 1);
    }
}

// ---------------- Kernel 3: final combine --------------------------------------
__global__ void k_final(const float* __restrict__ acc,
                        const int* __restrict__ flag,
                        float* __restrict__ out) {
    float wl = acc[0] / acc[1];
    float lp = LEN_P * acc[2] * (1.0f / BB);
    float bg = acc[3] / (float)(BB * (SS - 1) * VV);
    float tg = acc[4] / (float)(BB * (SS - 2) * VV);
    float ng = bg + ((*flag) ? 1.5f * tg : 0.f);
    out[0] = wl * 0.7f + lp * 0.2f + CHAR_W * ng * 0.1f;
}

extern "C" void kernel_launch(void* const* d_in, const int* in_sizes, int n_in,
                              void* d_out, int out_size, void* d_ws, size_t ws_size,
                              hipStream_t stream) {
    const float* x   = (const float*)d_in[0];   // [512,128,2048] f32
    const int*   tgt = (const int*)d_in[1];     // [512,128] i32
    float*       out = (float*)d_out;           // scalar f32

    float* ce    = (float*)d_ws;                              // 65536 f32
    int*   preds = (int*)((char*)d_ws + (size_t)BB * SS * 4); // 65536 i32
    float* acc   = (float*)((char*)d_ws + (size_t)2 * BB * SS * 4);
    int*   flag  = (int*)(acc + 5);

    k_rows<<<(BB * SS) / 4, 256, 0, stream>>>(x, tgt, ce, preds, acc, flag);
    k_batch<<<BB, 128, 0, stream>>>(tgt, preds, ce, acc, flag);
    k_final<<<1, 1, 0, stream>>>(acc, flag, out);
}